// Round 3
// baseline (412.398 us; speedup 1.0000x reference)
//
#include <hip/hip_runtime.h>

#define N_RAYS    131072
#define N_SAMPLES 128
#define FAR_DELTA 1e10f

#define THREADS_PER_RAY 4
#define SAMPLES_PER_THREAD (N_SAMPLES / THREADS_PER_RAY)   // 32
#define GROUPS 8                                            // 8 x float4 = 32 samples

// 4 threads per ray, 32 samples/thread, serial in-register cumprod.
// No LDS staging; all global loads are aligned float4 owned entirely by one
// thread (full cache-line utilization). Cross-thread combine = 4-lane
// prefix-product scan (2 shuffles) + 4-lane butterfly (8 shuffles).
__global__ __launch_bounds__(256) void VolumeRenderer_57612691308835_kernel(
    const float* __restrict__ density,      // [N, S]
    const float* __restrict__ feature,      // [N, S, 3]
    const float* __restrict__ depth,        // [N, S]
    float* __restrict__ out_feat,           // [N, 3]
    float* __restrict__ out_depth)          // [N]
{
    const int gtid = blockIdx.x * 256 + threadIdx.x;
    const int ray  = gtid >> 2;             // 4 consecutive lanes share a ray
    const int sub  = gtid & 3;              // which quarter of the ray

    const long sbase = (long)ray * N_SAMPLES + sub * SAMPLES_PER_THREAD;
    const float4* __restrict__ dep4p = (const float4*)(depth   + sbase);
    const float4* __restrict__ den4p = (const float4*)(density + sbase);
    const float4* __restrict__ f4p   = (const float4*)(feature + sbase * 3);

    // First depth group now; shuffle gives depth[sbase+32] (next sub's first).
    const float4 dep_first = dep4p[0];
    const float  next_depth = __shfl_down(dep_first.x, 1);  // valid when sub<3

    float Tloc = 1.0f;                       // local transmittance (starts at 1)
    float sfx = 0.f, sfy = 0.f, sfz = 0.f, sdd = 0.f;

    // carry: the last sample of each group waits for the next group's first
    // depth to form its delta.
    float c_dep = 0.f, c_den = 0.f, c_f0 = 0.f, c_f1 = 0.f, c_f2 = 0.f;

    auto process = [&](float den, float delta, float f0, float f1, float f2,
                       float d) {
        const float att = __expf(-den * delta);
        Tloc *= att;                         // inclusive T_i
        const float w = Tloc * (1.0f - att); // weights = T * (1 - att)
        sfx += w * f0;
        sfy += w * f1;
        sfz += w * f2;
        sdd += w * d;
    };

    #pragma unroll
    for (int g = 0; g < GROUPS; ++g) {
        const float4 dep4 = (g == 0) ? dep_first : dep4p[g];
        const float4 den4 = den4p[g];
        const float4 fA = f4p[3 * g + 0];
        const float4 fB = f4p[3 * g + 1];
        const float4 fC = f4p[3 * g + 2];

        if (g > 0)  // carried sample (4g-1): delta closes with this group's first depth
            process(c_den, dep4.x - c_dep, c_f0, c_f1, c_f2, c_dep);

        process(den4.x, dep4.y - dep4.x, fA.x, fA.y, fA.z, dep4.x);
        process(den4.y, dep4.z - dep4.y, fA.w, fB.x, fB.y, dep4.y);
        process(den4.z, dep4.w - dep4.z, fB.z, fB.w, fC.x, dep4.z);

        c_dep = dep4.w; c_den = den4.w;      // sample 4g+3 carried forward
        c_f0 = fC.y; c_f1 = fC.z; c_f2 = fC.w;
    }

    // Final carried sample (local index 31). Ray's very last sample -> FAR_DELTA.
    {
        const float delta = (sub == 3) ? FAR_DELTA : (next_depth - c_dep);
        process(c_den, delta, c_f0, c_f1, c_f2, c_dep);
    }

    // ---- combine the 4 sub-threads of this ray ----
    // Inclusive product-scan of Tloc over the quad (guards confine to quad).
    float p = Tloc;
    float v = __shfl_up(p, 1); if (sub >= 1) p *= v;
    v       = __shfl_up(p, 2); if (sub >= 2) p *= v;
    float excl = __shfl_up(p, 1);            // product of preceding subs' T
    if (sub == 0) excl = 1.0f;

    sfx *= excl; sfy *= excl; sfz *= excl; sdd *= excl;

    // Butterfly sum within the quad (xor 1, xor 2 stay inside the quad).
    sfx += __shfl_xor(sfx, 1); sfx += __shfl_xor(sfx, 2);
    sfy += __shfl_xor(sfy, 1); sfy += __shfl_xor(sfy, 2);
    sfz += __shfl_xor(sfz, 1); sfz += __shfl_xor(sfz, 2);
    sdd += __shfl_xor(sdd, 1); sdd += __shfl_xor(sdd, 2);

    if (sub == 0) {
        out_feat[ray * 3 + 0] = sfx;
        out_feat[ray * 3 + 1] = sfy;
        out_feat[ray * 3 + 2] = sfz;
        out_depth[ray]        = sdd;
    }
}

extern "C" void kernel_launch(void* const* d_in, const int* in_sizes, int n_in,
                              void* d_out, int out_size, void* d_ws, size_t ws_size,
                              hipStream_t stream) {
    const float* density = (const float*)d_in[0];   // [N, S]
    const float* feature = (const float*)d_in[1];   // [N, S, 3]
    const float* depth   = (const float*)d_in[2];   // [N, S]

    float* out_feat  = (float*)d_out;                       // [N, 3]
    float* out_depth = (float*)d_out + (long)N_RAYS * 3;    // [N]

    const int total_threads = N_RAYS * THREADS_PER_RAY;     // 524288
    const int grid = total_threads / 256;                   // 2048 blocks
    VolumeRenderer_57612691308835_kernel<<<grid, 256, 0, stream>>>(
        density, feature, depth, out_feat, out_depth);
}

// Round 4
// 372.944 us; speedup vs baseline: 1.1058x; 1.1058x over previous
//
#include <hip/hip_runtime.h>

#define N_RAYS    131072
#define N_SAMPLES 128
#define FAR_DELTA 1e10f

#define THREADS_PER_RAY 8
#define SPT (N_SAMPLES / THREADS_PER_RAY)     // 16 samples per thread

// 8 threads per ray, 16 samples/thread, serial in-register cumprod.
// Per-thread contiguous regions (depth/density 64 B, feature 192 B) are
// loaded as float4s whose cache lines are fully consumed by adjacent
// instructions of the same wave -> no partial-line over-fetch (R2's bug).
// Cross-thread combine: 3-step prefix-product scan + xor-{1,2,4} butterfly
// confined to each 8-lane group (~17 DS instrs/wave total).
__global__ __launch_bounds__(256) void VolumeRenderer_57612691308835_kernel(
    const float* __restrict__ density,      // [N, S]
    const float* __restrict__ feature,      // [N, S, 3]
    const float* __restrict__ depth,        // [N, S]
    float* __restrict__ out_feat,           // [N, 3]
    float* __restrict__ out_depth)          // [N]
{
    const int gtid = blockIdx.x * 256 + threadIdx.x;
    const int ray  = gtid >> 3;             // 8 consecutive lanes per ray
    const int sub  = gtid & 7;

    const long sbase = (long)ray * N_SAMPLES + sub * SPT;
    const float4* __restrict__ dp4 = (const float4*)(depth   + sbase);
    const float4* __restrict__ dn4 = (const float4*)(density + sbase);
    const float4* __restrict__ ft4 = (const float4*)(feature + sbase * 3);

    // ---- load everything for this thread's 16 samples into registers ----
    float dep[SPT + 1], den[SPT], f[SPT * 3];
    #pragma unroll
    for (int g = 0; g < SPT / 4; ++g) {
        const float4 v = dp4[g];
        dep[4*g+0] = v.x; dep[4*g+1] = v.y; dep[4*g+2] = v.z; dep[4*g+3] = v.w;
    }
    #pragma unroll
    for (int g = 0; g < SPT / 4; ++g) {
        const float4 v = dn4[g];
        den[4*g+0] = v.x; den[4*g+1] = v.y; den[4*g+2] = v.z; den[4*g+3] = v.w;
    }
    #pragma unroll
    for (int g = 0; g < SPT * 3 / 4; ++g) {   // 12 float4s, adjacent issue
        const float4 v = ft4[g];
        f[4*g+0] = v.x; f[4*g+1] = v.y; f[4*g+2] = v.z; f[4*g+3] = v.w;
    }

    // next sub-thread's first depth (same ray when sub<7; sub==7 uses sentinel)
    dep[SPT] = __shfl_down(dep[0], 1);

    // ---- serial inclusive cumprod + weighted accumulation ----
    float Tloc = 1.0f;
    float sfx = 0.f, sfy = 0.f, sfz = 0.f, sdd = 0.f;
    #pragma unroll
    for (int i = 0; i < SPT; ++i) {
        const float delta = (sub == 7 && i == SPT - 1) ? FAR_DELTA
                                                       : (dep[i + 1] - dep[i]);
        const float att = __expf(-den[i] * delta);
        Tloc *= att;                          // inclusive T_i (local)
        const float w = Tloc * (1.0f - att);  // weight_i / prefix
        sfx += w * f[3*i + 0];
        sfy += w * f[3*i + 1];
        sfz += w * f[3*i + 2];
        sdd += w * dep[i];
    }

    // ---- combine the 8 sub-threads of this ray ----
    // inclusive product-scan of Tloc over the 8-lane group
    float p = Tloc, v;
    v = __shfl_up(p, 1); if (sub >= 1) p *= v;
    v = __shfl_up(p, 2); if (sub >= 2) p *= v;
    v = __shfl_up(p, 4); if (sub >= 4) p *= v;
    float excl = __shfl_up(p, 1);             // product of preceding subs
    if (sub == 0) excl = 1.0f;

    sfx *= excl; sfy *= excl; sfz *= excl; sdd *= excl;

    // butterfly sum within the 8-lane group
    #pragma unroll
    for (int off = 1; off <= 4; off <<= 1) {
        sfx += __shfl_xor(sfx, off);
        sfy += __shfl_xor(sfy, off);
        sfz += __shfl_xor(sfz, off);
        sdd += __shfl_xor(sdd, off);
    }

    if (sub == 0) {
        out_feat[ray * 3 + 0] = sfx;
        out_feat[ray * 3 + 1] = sfy;
        out_feat[ray * 3 + 2] = sfz;
        out_depth[ray]        = sdd;
    }
}

extern "C" void kernel_launch(void* const* d_in, const int* in_sizes, int n_in,
                              void* d_out, int out_size, void* d_ws, size_t ws_size,
                              hipStream_t stream) {
    const float* density = (const float*)d_in[0];   // [N, S]
    const float* feature = (const float*)d_in[1];   // [N, S, 3]
    const float* depth   = (const float*)d_in[2];   // [N, S]

    float* out_feat  = (float*)d_out;                       // [N, 3]
    float* out_depth = (float*)d_out + (long)N_RAYS * 3;    // [N]

    const int total_threads = N_RAYS * THREADS_PER_RAY;     // 1048576
    const int grid = total_threads / 256;                   // 4096 blocks
    VolumeRenderer_57612691308835_kernel<<<grid, 256, 0, stream>>>(
        density, feature, depth, out_feat, out_depth);
}

// Round 6
// 371.549 us; speedup vs baseline: 1.1099x; 1.0038x over previous
//
#include <hip/hip_runtime.h>

#define N_RAYS    131072
#define N_SAMPLES 128
#define FAR_DELTA 1e10f

#define TPB 256
#define TPR 16                        // threads per ray
#define SPT (N_SAMPLES / TPR)         // 8 samples per thread
#define RPB (TPB / TPR)               // 16 rays per block

// LDS layout: data viewed as 16-word chunks; chunk q lives at words
// [20*q, 20*q+16) -- 4 words of pad per chunk, NO skew (R4's skew wrapped
// every 64 chunks and made chunks overlap). All three access patterns
// (linear b128 store, 20*c+{0,8} read, W+4*(W>>4) read) give a uniform
// 8 words/bank per wave instruction -- the minimum for 256 word accesses.
// Phase A: density chunks [0,128), depth chunks [128,256).
// Phase B (reuses buffer): feature chunks [0,384).
#define LDS_WORDS (20 * 384 + 16)     // 7696 words = 30784 B

__device__ __forceinline__ int lds_addr(int chunk, int j) {
    return 20 * chunk + j;
}
__device__ __forceinline__ int lds_addr_w(int chunk_base, int W) {
    return lds_addr(chunk_base + (W >> 4), W & 15);
}

__global__ __launch_bounds__(256) void VolumeRenderer_57612691308835_kernel(
    const float* __restrict__ density,      // [N, S]
    const float* __restrict__ feature,      // [N, S, 3]
    const float* __restrict__ depth,        // [N, S]
    float* __restrict__ out_feat,           // [N, 3]
    float* __restrict__ out_depth)          // [N]
{
    __shared__ float lds[LDS_WORDS];

    const int tid = threadIdx.x;
    const int r   = tid >> 4;               // ray within block
    const int sub = tid & 15;               // 16-lane group position
    const int blockRay0 = blockIdx.x * RPB;

    // ---- issue ALL global loads up front; perfectly coalesced float4 ----
    const float4* gden = (const float4*)(density + (long)blockRay0 * N_SAMPLES);
    const float4* gdep = (const float4*)(depth   + (long)blockRay0 * N_SAMPLES);
    const float4* gft  = (const float4*)(feature + (long)blockRay0 * N_SAMPLES * 3);
    float4 ld_den[2], ld_dep[2], ld_ft[6];
    #pragma unroll
    for (int s = 0; s < 2; ++s) ld_den[s] = gden[tid + s * 256];
    #pragma unroll
    for (int s = 0; s < 2; ++s) ld_dep[s] = gdep[tid + s * 256];
    #pragma unroll
    for (int s = 0; s < 6; ++s) ld_ft[s]  = gft[tid + s * 256];

    // ---- phase A: stage density + depth (padded chunk layout) ----
    #pragma unroll
    for (int s = 0; s < 2; ++s) {
        const int W = s * 1024 + 4 * tid;
        *(float4*)&lds[lds_addr_w(0,   W)] = ld_den[s];
        *(float4*)&lds[lds_addr_w(128, W)] = ld_dep[s];
    }
    __syncthreads();

    // ---- read this thread's 8 samples of den/dep from LDS ----
    // words r*128 + 8*sub + i  ->  chunk 8r + (sub>>1), j = 8*(sub&1) + i
    float den[SPT], dep[SPT];
    {
        const int cA = 8 * r + (sub >> 1);
        const int j0 = 8 * (sub & 1);
        #pragma unroll
        for (int h = 0; h < 2; ++h) {
            const float4 v = *(const float4*)&lds[lds_addr(cA,       j0 + 4 * h)];
            const float4 w = *(const float4*)&lds[lds_addr(128 + cA, j0 + 4 * h)];
            den[4*h+0] = v.x; den[4*h+1] = v.y; den[4*h+2] = v.z; den[4*h+3] = v.w;
            dep[4*h+0] = w.x; dep[4*h+1] = w.y; dep[4*h+2] = w.z; dep[4*h+3] = w.w;
        }
    }
    const float next_dep = __shfl_down(dep[0], 1);   // neighbor sub's first depth

    // ---- serial cumprod + weights (local prefix); depth-sum now ----
    float w8[SPT];
    float Tloc = 1.0f, sdd = 0.f;
    #pragma unroll
    for (int i = 0; i < SPT; ++i) {
        const float dnext = (i < SPT - 1) ? dep[i + 1]
                          : (sub == TPR - 1 ? dep[i] + FAR_DELTA : next_dep);
        const float att = __expf(-den[i] * (dnext - dep[i]));
        Tloc *= att;
        w8[i] = Tloc * (1.0f - att);
        sdd += w8[i] * dep[i];
    }

    // ---- 16-lane exclusive prefix product of Tloc ----
    float p = Tloc, v;
    v = __shfl_up(p, 1); if (sub >= 1) p *= v;
    v = __shfl_up(p, 2); if (sub >= 2) p *= v;
    v = __shfl_up(p, 4); if (sub >= 4) p *= v;
    v = __shfl_up(p, 8); if (sub >= 8) p *= v;
    float excl = __shfl_up(p, 1);
    if (sub == 0) excl = 1.0f;

    __syncthreads();                                 // phase A reads done

    // ---- phase B: stage features into the same buffer ----
    #pragma unroll
    for (int s = 0; s < 6; ++s) {
        const int W = s * 1024 + 4 * tid;
        *(float4*)&lds[lds_addr_w(0, W)] = ld_ft[s];
    }
    __syncthreads();

    // ---- read this thread's 24 feature floats; accumulate ----
    // words r*384 + 24*sub + 4k, k=0..5 (4-aligned, never crosses a chunk)
    float sfx = 0.f, sfy = 0.f, sfz = 0.f;
    {
        const int Wbase = r * 384 + 24 * sub;
        float f[24];
        #pragma unroll
        for (int k = 0; k < 6; ++k) {
            const float4 q = *(const float4*)&lds[lds_addr_w(0, Wbase + 4 * k)];
            f[4*k+0] = q.x; f[4*k+1] = q.y; f[4*k+2] = q.z; f[4*k+3] = q.w;
        }
        #pragma unroll
        for (int i = 0; i < SPT; ++i) {
            sfx += w8[i] * f[3*i + 0];
            sfy += w8[i] * f[3*i + 1];
            sfz += w8[i] * f[3*i + 2];
        }
    }

    // ---- apply prefix, butterfly-sum within the 16-lane group ----
    sfx *= excl; sfy *= excl; sfz *= excl; sdd *= excl;
    #pragma unroll
    for (int off = 1; off <= 8; off <<= 1) {
        sfx += __shfl_xor(sfx, off);
        sfy += __shfl_xor(sfy, off);
        sfz += __shfl_xor(sfz, off);
        sdd += __shfl_xor(sdd, off);
    }

    if (sub == 0) {
        const int ray = blockRay0 + r;
        out_feat[ray * 3 + 0] = sfx;
        out_feat[ray * 3 + 1] = sfy;
        out_feat[ray * 3 + 2] = sfz;
        out_depth[ray]        = sdd;
    }
}

extern "C" void kernel_launch(void* const* d_in, const int* in_sizes, int n_in,
                              void* d_out, int out_size, void* d_ws, size_t ws_size,
                              hipStream_t stream) {
    const float* density = (const float*)d_in[0];   // [N, S]
    const float* feature = (const float*)d_in[1];   // [N, S, 3]
    const float* depth   = (const float*)d_in[2];   // [N, S]

    float* out_feat  = (float*)d_out;                       // [N, 3]
    float* out_depth = (float*)d_out + (long)N_RAYS * 3;    // [N]

    const int grid = N_RAYS / RPB;                          // 8192 blocks
    VolumeRenderer_57612691308835_kernel<<<grid, TPB, 0, stream>>>(
        density, feature, depth, out_feat, out_depth);
}